// Round 1
// baseline (194.291 us; speedup 1.0000x reference)
//
#include <hip/hip_runtime.h>

// Prototype loss: loss = 0.5*mean_B( mean_D((x-p)^2) ) + 0.5*mean_B( 1 - cos(x,p) )
// x: [B, 512] f32, label: [B] i32, proto: [1000, 512] f32, out: scalar f32.
// Memory-bound: one pass over x (128 MB). One wave per row, float4 loads.

constexpr int D_DIM = 512;            // feature dim (fixed by problem)
constexpr float COS_EPS = 1e-8f;
constexpr int NBLOCKS = 2048;         // per-block partials in d_ws (8 KB)

__global__ __launch_bounds__(256) void proto_loss_partial(
    const float* __restrict__ x,
    const int* __restrict__ label,
    const float* __restrict__ proto,
    float* __restrict__ partials,
    int B)
{
    const int lane = threadIdx.x & 63;
    const int wave = threadIdx.x >> 6;
    const int wavesPerBlock = blockDim.x >> 6;      // 4
    const int gwave = blockIdx.x * wavesPerBlock + wave;
    const int nwaves = gridDim.x * wavesPerBlock;

    float acc = 0.0f;  // meaningful on lane 0 only
    for (int row = gwave; row < B; row += nwaves) {
        const float4* __restrict__ xr =
            reinterpret_cast<const float4*>(x + (size_t)row * D_DIM);
        const int lbl = label[row];
        const float4* __restrict__ pr =
            reinterpret_cast<const float4*>(proto + (size_t)lbl * D_DIM);

        // 128 float4 per row; lane handles [lane] and [lane+64] — fully coalesced
        float4 x0 = xr[lane];
        float4 p0 = pr[lane];
        float4 x1 = xr[lane + 64];
        float4 p1 = pr[lane + 64];

        float dot = x0.x*p0.x + x0.y*p0.y + x0.z*p0.z + x0.w*p0.w
                  + x1.x*p1.x + x1.y*p1.y + x1.z*p1.z + x1.w*p1.w;
        float sx  = x0.x*x0.x + x0.y*x0.y + x0.z*x0.z + x0.w*x0.w
                  + x1.x*x1.x + x1.y*x1.y + x1.z*x1.z + x1.w*x1.w;
        float sp  = p0.x*p0.x + p0.y*p0.y + p0.z*p0.z + p0.w*p0.w
                  + p1.x*p1.x + p1.y*p1.y + p1.z*p1.z + p1.w*p1.w;

        // wave-64 reduction of the three sums
        #pragma unroll
        for (int off = 32; off > 0; off >>= 1) {
            dot += __shfl_down(dot, off, 64);
            sx  += __shfl_down(sx,  off, 64);
            sp  += __shfl_down(sp,  off, 64);
        }

        if (lane == 0) {
            float sse   = sx - 2.0f*dot + sp;                  // sum((x-p)^2)
            float denom = fmaxf(sqrtf(sx) * sqrtf(sp), COS_EPS);
            float cosv  = dot / denom;
            acc += 0.5f * (sse * (1.0f / D_DIM)) + 0.5f * (1.0f - cosv);
        }
    }

    __shared__ float smem[8];
    if (lane == 0) smem[wave] = acc;
    __syncthreads();
    if (threadIdx.x == 0) {
        float s = 0.0f;
        for (int w = 0; w < wavesPerBlock; ++w) s += smem[w];
        partials[blockIdx.x] = s;
    }
}

__global__ __launch_bounds__(1024) void proto_loss_final(
    const float* __restrict__ partials, int n, float invB,
    float* __restrict__ out)
{
    __shared__ float smem[16];
    const int lane = threadIdx.x & 63;
    const int wave = threadIdx.x >> 6;

    float v = 0.0f;
    for (int i = threadIdx.x; i < n; i += blockDim.x) v += partials[i];

    #pragma unroll
    for (int off = 32; off > 0; off >>= 1) v += __shfl_down(v, off, 64);

    if (lane == 0) smem[wave] = v;
    __syncthreads();
    if (threadIdx.x == 0) {
        float s = 0.0f;
        const int nw = blockDim.x >> 6;
        for (int w = 0; w < nw; ++w) s += smem[w];
        out[0] = s * invB;
    }
}

extern "C" void kernel_launch(void* const* d_in, const int* in_sizes, int n_in,
                              void* d_out, int out_size, void* d_ws, size_t ws_size,
                              hipStream_t stream) {
    const float* x     = (const float*)d_in[0];
    const int*   label = (const int*)d_in[1];
    const float* proto = (const float*)d_in[2];
    float* out = (float*)d_out;
    float* partials = (float*)d_ws;   // NBLOCKS floats, fully overwritten each call

    const int B = in_sizes[1];        // 65536; in_sizes[0] = B*D

    proto_loss_partial<<<NBLOCKS, 256, 0, stream>>>(x, label, proto, partials, B);
    proto_loss_final<<<1, 1024, 0, stream>>>(partials, NBLOCKS, 1.0f / (float)B, out);
}

// Round 2
// 194.086 us; speedup vs baseline: 1.0011x; 1.0011x over previous
//
#include <hip/hip_runtime.h>

// Prototype loss: loss = 0.5*mean_B( mean_D((x-p)^2) ) + 0.5*mean_B( 1 - cos(x,p) )
// x: [B, 512] f32, label: [B] i32, proto: [1000, 512] f32, out: scalar f32.
//
// R2 design: 16 lanes per row, 4 rows in flight per wave.
//  - per lane per row: 8 float4 x-loads + 8 float4 proto-loads (16 indep loads -> high MLP)
//  - 4-step shuffle reduce within 16-lane segments (was 6-step over 64)
//  - wave handles 8 consecutive rows in 2 outer iterations (L2-friendly)

constexpr int D_DIM   = 512;
constexpr float COS_EPS = 1e-8f;
constexpr int NBLOCKS = 2048;                 // per-block partials in d_ws
constexpr int G       = 16;                   // lanes per row
constexpr int F4      = (D_DIM / 4) / G;      // 8 float4 per lane per row
constexpr int RPP     = 64 / G;               // 4 rows per wave per pass

__global__ __launch_bounds__(256) void proto_loss_partial(
    const float* __restrict__ x,
    const int* __restrict__ label,
    const float* __restrict__ proto,
    float* __restrict__ partials,
    int B)
{
    const int lane = threadIdx.x & 63;
    const int wave = threadIdx.x >> 6;
    const int sub  = lane & (G - 1);          // 0..15 within row group
    const int grp  = lane >> 4;               // 0..3: which row of the pass
    const int wavesPerBlock = blockDim.x >> 6;               // 4
    const int gwave  = blockIdx.x * wavesPerBlock + wave;    // 0..8191
    const int nwaves = gridDim.x * wavesPerBlock;

    // contiguous row chunk per wave (ceil-div for safety)
    const int rowsPerWave = (B + nwaves - 1) / nwaves;       // 8 for B=65536
    const int base = gwave * rowsPerWave;

    float acc = 0.0f;   // per-lane accumulation; only sub==0 lanes get row terms

    for (int r0 = 0; r0 < rowsPerWave; r0 += RPP) {
        const int row = base + r0 + grp;
        if (row < B) {
            const int lbl = label[row];
            const float4* __restrict__ xr =
                reinterpret_cast<const float4*>(x + (size_t)row * D_DIM);
            const float4* __restrict__ pr =
                reinterpret_cast<const float4*>(proto + (size_t)lbl * D_DIM);

            float dot = 0.0f, sx = 0.0f, sp = 0.0f;
            #pragma unroll
            for (int k = 0; k < F4; ++k) {
                float4 xv = xr[sub + k * G];
                float4 pv = pr[sub + k * G];
                dot += xv.x*pv.x + xv.y*pv.y + xv.z*pv.z + xv.w*pv.w;
                sx  += xv.x*xv.x + xv.y*xv.y + xv.z*xv.z + xv.w*xv.w;
                sp  += pv.x*pv.x + pv.y*pv.y + pv.z*pv.z + pv.w*pv.w;
            }

            // reduce within the 16-lane segment
            #pragma unroll
            for (int off = G / 2; off > 0; off >>= 1) {
                dot += __shfl_down(dot, off, G);
                sx  += __shfl_down(sx,  off, G);
                sp  += __shfl_down(sp,  off, G);
            }

            if (sub == 0) {
                float sse   = sx - 2.0f * dot + sp;              // sum((x-p)^2)
                float denom = fmaxf(sqrtf(sx) * sqrtf(sp), COS_EPS);
                acc += 0.5f * (sse * (1.0f / D_DIM)) + 0.5f * (1.0f - dot / denom);
            }
        }
    }

    // reduce acc across the wave (non-sub0 lanes hold 0)
    #pragma unroll
    for (int off = 32; off > 0; off >>= 1) acc += __shfl_down(acc, off, 64);

    __shared__ float smem[8];
    if (lane == 0) smem[wave] = acc;
    __syncthreads();
    if (threadIdx.x == 0) {
        float s = 0.0f;
        for (int w = 0; w < wavesPerBlock; ++w) s += smem[w];
        partials[blockIdx.x] = s;
    }
}

__global__ __launch_bounds__(1024) void proto_loss_final(
    const float* __restrict__ partials, int n, float invB,
    float* __restrict__ out)
{
    __shared__ float smem[16];
    const int lane = threadIdx.x & 63;
    const int wave = threadIdx.x >> 6;

    float v = 0.0f;
    for (int i = threadIdx.x; i < n; i += blockDim.x) v += partials[i];

    #pragma unroll
    for (int off = 32; off > 0; off >>= 1) v += __shfl_down(v, off, 64);

    if (lane == 0) smem[wave] = v;
    __syncthreads();
    if (threadIdx.x == 0) {
        float s = 0.0f;
        const int nw = blockDim.x >> 6;
        for (int w = 0; w < nw; ++w) s += smem[w];
        out[0] = s * invB;
    }
}

extern "C" void kernel_launch(void* const* d_in, const int* in_sizes, int n_in,
                              void* d_out, int out_size, void* d_ws, size_t ws_size,
                              hipStream_t stream) {
    const float* x     = (const float*)d_in[0];
    const int*   label = (const int*)d_in[1];
    const float* proto = (const float*)d_in[2];
    float* out = (float*)d_out;
    float* partials = (float*)d_ws;   // NBLOCKS floats, fully overwritten each call

    const int B = in_sizes[1];        // 65536; in_sizes[0] = B*D

    proto_loss_partial<<<NBLOCKS, 256, 0, stream>>>(x, label, proto, partials, B);
    proto_loss_final<<<1, 1024, 0, stream>>>(partials, NBLOCKS, 1.0f / (float)B, out);
}